// Round 15
// baseline (760.293 us; speedup 1.0000x reference)
//
#include <hip/hip_runtime.h>
#include <hip/hip_bf16.h>
#include <math.h>

#define N_NODES 50000
#define MPAD 50048      // padded row count for GEMM A-tiles (128-multiple)
#define N_EDGES 800000
#define HCH 256
#define NHEAD 4
#define HIDC 64
#define NCLS 349
#define F_IN 128

typedef short short8 __attribute__((ext_vector_type(8)));
typedef float floatx4 __attribute__((ext_vector_type(4)));

// ---------------- edge_index storage-width detection ----------------
__global__ void k_detect(const unsigned* ei, int* flag) {
    if (blockIdx.x == 0 && threadIdx.x == 0) {
        int i64 = 1;
        for (int e = 0; e < 64; e++)
            if (ei[2 * e + 1] != 0u) { i64 = 0; break; }
        *flag = i64;
    }
}

__device__ __forceinline__ void edge_sd(const int* ei, int e, int i64, int& s, int& d) {
    if (i64) {
        const long long* p = (const long long*)ei;
        s = (int)p[e]; d = (int)p[N_EDGES + e];
    } else {
        s = ei[e]; d = ei[N_EDGES + e];
    }
}

// ---------------- CSR build (by dst) ----------------
__global__ void k_deg(const int* ei, const int* flag, int* deg) {
    int e = blockIdx.x * 256 + threadIdx.x;
    if (e >= N_EDGES) return;
    int s, d; edge_sd(ei, e, *flag, s, d);
    atomicAdd(&deg[d], 1);
}

__global__ __launch_bounds__(256) void k_scan1(const int* __restrict__ deg,
                                               int* __restrict__ rowptr,
                                               int* __restrict__ bsum) {
    __shared__ int sd[256];
    int t = threadIdx.x;
    int base = blockIdx.x * 1024 + t * 4;
    int d0 = 0, d1 = 0, d2 = 0, d3 = 0;
    if (base + 3 < N_NODES) {
        int4 v = *(const int4*)(deg + base);
        d0 = v.x; d1 = v.y; d2 = v.z; d3 = v.w;
    } else {
        if (base + 0 < N_NODES) d0 = deg[base + 0];
        if (base + 1 < N_NODES) d1 = deg[base + 1];
        if (base + 2 < N_NODES) d2 = deg[base + 2];
        if (base + 3 < N_NODES) d3 = deg[base + 3];
    }
    int ts = d0 + d1 + d2 + d3;
    sd[t] = ts;
    __syncthreads();
    #pragma unroll
    for (int off = 1; off < 256; off <<= 1) {
        int v = (t >= off) ? sd[t - off] : 0;
        __syncthreads();
        sd[t] += v;
        __syncthreads();
    }
    int excl = (t == 0) ? 0 : sd[t - 1];
    if (base + 0 < N_NODES) rowptr[base + 0] = excl;
    if (base + 1 < N_NODES) rowptr[base + 1] = excl + d0;
    if (base + 2 < N_NODES) rowptr[base + 2] = excl + d0 + d1;
    if (base + 3 < N_NODES) rowptr[base + 3] = excl + d0 + d1 + d2;
    if (t == 255) bsum[blockIdx.x] = sd[255];
}

__global__ void k_scan2(int* __restrict__ bsum, int nb, int* __restrict__ rowptr) {
    int lane = threadIdx.x;
    int orig = (lane < nb) ? bsum[lane] : 0;
    int v = orig;
    #pragma unroll
    for (int off = 1; off < 64; off <<= 1) {
        int tv = __shfl_up(v, off, 64);
        if (lane >= off) v += tv;
    }
    if (lane < nb) bsum[lane] = v - orig;
    if (lane == 0) rowptr[N_NODES] = N_EDGES;
}

__global__ __launch_bounds__(256) void k_scan3(int* __restrict__ rowptr,
                                               const int* __restrict__ bsum) {
    int base = blockIdx.x * 1024 + threadIdx.x * 4;
    int off = bsum[blockIdx.x];
    if (base + 3 < N_NODES) {
        int4 v = *(int4*)(rowptr + base);
        v.x += off; v.y += off; v.z += off; v.w += off;
        *(int4*)(rowptr + base) = v;
    } else {
        for (int j = 0; j < 4; j++)
            if (base + j < N_NODES) rowptr[base + j] += off;
    }
}

__global__ void k_fill(const int* ei, const int* flag, const int* __restrict__ rowptr,
                       int* cursor, int* __restrict__ esrc) {
    int e = blockIdx.x * 256 + threadIdx.x;
    if (e >= N_EDGES) return;
    int s, d; edge_sd(ei, e, *flag, s, d);
    int pos = atomicAdd(&cursor[d], 1);
    esrc[rowptr[d] + pos] = s;
}

// ---------------- attention-score folding ----------------
__global__ void k_wtilde(const float* __restrict__ ws, const float* __restrict__ wd,
                         const float* __restrict__ atts, const float* __restrict__ attd,
                         float* __restrict__ wt, int d) {
    int id = blockIdx.x * 256 + threadIdx.x;
    if (id >= d * 8) return;
    int j = id & 7, k = id >> 3;
    const float* w = (j < 4) ? ws : wd;
    const float* at = (j < 4) ? atts : attd;
    int h = j & 3;
    float s = 0.f;
    for (int c = 0; c < HIDC; c++) s += w[k * HCH + h * HIDC + c] * at[h * HIDC + c];
    wt[k * 8 + j] = s;
}

// ---------------- bf16 helpers ----------------
__device__ __forceinline__ unsigned short b16(float v) {
    __hip_bfloat16 t = __float2bfloat16(v);
    return *(unsigned short*)&t;
}

__device__ __forceinline__ float bfu(unsigned short u) {
    unsigned v = (unsigned)u << 16;
    return __builtin_bit_cast(float, v);
}

__global__ __launch_bounds__(256) void k_xcast(const float* __restrict__ x,
                                               unsigned short* __restrict__ xb) {
    size_t tot = (size_t)N_NODES * 128 / 4;
    for (size_t i = (size_t)blockIdx.x * 256 + threadIdx.x; i < tot;
         i += (size_t)gridDim.x * 256) {
        float4 v = *(const float4*)(x + i * 4);
        ushort4 o = {b16(v.x), b16(v.y), b16(v.z), b16(v.w)};
        *(ushort4*)(xb + i * 4) = o;
    }
}

// fused weight, transposed, plain bf16: Bt[c][k], c in [0,640)
__global__ void k_wcat_t(const float* __restrict__ ws, const float* __restrict__ lw,
                         const float* __restrict__ wtil, int K,
                         unsigned short* __restrict__ Bb) {
    int id = blockIdx.x * 256 + threadIdx.x;
    if (id >= 640 * K) return;
    int c = id / K, k = id % K;
    float v;
    if (c < 256) v = ws[(size_t)k * 256 + c];
    else if (c < 512) v = lw[(size_t)k * 256 + (c - 256)];
    else if (c < 520) v = wtil[(size_t)k * 8 + (c - 512)];
    else v = 0.f;
    Bb[(size_t)c * K + k] = b16(v);
}

__global__ void k_fcw_t(const float* __restrict__ fcw, int K,
                        unsigned short* __restrict__ Bb) {
    int id = blockIdx.x * 256 + threadIdx.x;
    if (id >= 384 * K) return;
    int c = id / K, k = id % K;
    float v = (c < NCLS) ? fcw[(size_t)k * NCLS + c] : 0.f;
    Bb[(size_t)c * K + k] = b16(v);
}

// ---------------- global_load_lds helper ----------------
__device__ __forceinline__ void gload16(const void* g, void* l) {
    __builtin_amdgcn_global_load_lds(
        (const __attribute__((address_space(1))) void*)g,
        (__attribute__((address_space(3))) void*)l, 16, 0, 0);
}

// ---------------- 2-phase MFMA GEMM, counted vmcnt + dead-fragment skip ----
// Epilogue writes group-sharded layouts: xsb2[g][N][32], linb2[g][N][32]
// (g = c>>5) so k_agg can channel-shard across XCDs.
__global__ __launch_bounds__(256) void k_gemm1(
    const unsigned short* __restrict__ Ab,
    const unsigned short* __restrict__ Bb,
    float* __restrict__ C, int ldc, __hip_bfloat16* __restrict__ xsb,
    __hip_bfloat16* __restrict__ linbb, float* __restrict__ aout,
    const float* __restrict__ bias, int M, int K, int Nc) {
    __shared__ unsigned short sA[2][4096];
    __shared__ unsigned short sB[2][4096];
    int tid = threadIdx.x;
    int lane = tid & 63, wave = tid >> 6;
    int wm = wave >> 1, wn = wave & 1;
    int row0 = blockIdx.x * 128, col0 = blockIdx.y * 128;

    int rowq[2], kcq[2];
    #pragma unroll
    for (int q = 0; q < 2; q++) {
        int lds16 = wave * 128 + q * 64 + lane;
        int line = lds16 >> 3;
        int slot0 = (lds16 & 7) ^ (line & 7);
        rowq[q] = (line << 1) | (slot0 >> 2);
        kcq[q] = slot0 & 3;
    }
    int kc = lane >> 4, fr = lane & 15;
    int offA[4], offB[4];
    bool usej[4];
    #pragma unroll
    for (int i = 0; i < 4; i++) {
        int ar = wm * 64 + i * 16 + fr;
        int ln = ar >> 1;
        int sl = (((ar & 1) << 2) | kc) ^ (ln & 7);
        offA[i] = ln * 128 + sl * 16;
        int bc = wn * 64 + i * 16 + fr;
        ln = bc >> 1;
        sl = (((bc & 1) << 2) | kc) ^ (ln & 7);
        offB[i] = ln * 128 + sl * 16;
        usej[i] = (col0 + wn * 64 + i * 16) < Nc;   // dead-column fragment skip
    }

    const int nt = K >> 5;
    #pragma unroll
    for (int q = 0; q < 2; q++) {
        int lb = wave * 2048 + q * 1024;
        gload16(Ab + (size_t)(row0 + rowq[q]) * K + kcq[q] * 8, (char*)sA[0] + lb);
        gload16(Bb + (size_t)(col0 + rowq[q]) * K + kcq[q] * 8, (char*)sB[0] + lb);
    }

    floatx4 acc[4][4] = {};
    int cur = 0;
    for (int t = 0; t < nt; t++) {
        if (t + 1 < nt) {
            int k0 = (t + 1) << 5;
            #pragma unroll
            for (int q = 0; q < 2; q++) {
                int lb = wave * 2048 + q * 1024;
                gload16(Ab + (size_t)(row0 + rowq[q]) * K + k0 + kcq[q] * 8, (char*)sA[cur ^ 1] + lb);
                gload16(Bb + (size_t)(col0 + rowq[q]) * K + k0 + kcq[q] * 8, (char*)sB[cur ^ 1] + lb);
            }
            asm volatile("s_waitcnt vmcnt(4)" ::: "memory");
        } else {
            asm volatile("s_waitcnt vmcnt(0)" ::: "memory");
        }
        __builtin_amdgcn_s_barrier();
        __builtin_amdgcn_sched_barrier(0);
        short8 fah[4], fbh[4];
        #pragma unroll
        for (int i = 0; i < 4; i++) {
            fah[i] = *(const short8*)((const char*)sA[cur] + offA[i]);
            if (usej[i]) fbh[i] = *(const short8*)((const char*)sB[cur] + offB[i]);
        }
        #pragma unroll
        for (int i = 0; i < 4; i++)
            #pragma unroll
            for (int j = 0; j < 4; j++)
                if (usej[j])
                    acc[i][j] = __builtin_amdgcn_mfma_f32_16x16x32_bf16(fah[i], fbh[j], acc[i][j], 0, 0, 0);
        asm volatile("s_waitcnt lgkmcnt(0)" ::: "memory");
        __builtin_amdgcn_s_barrier();
        __builtin_amdgcn_sched_barrier(0);
        cur ^= 1;
    }
    #pragma unroll
    for (int i = 0; i < 4; i++) {
        #pragma unroll
        for (int j = 0; j < 4; j++) {
            if (!usej[j]) continue;
            int c = col0 + wn * 64 + j * 16 + fr;
            if (c >= Nc) continue;
            float bv = bias ? bias[c] : 0.f;
            #pragma unroll
            for (int q = 0; q < 4; q++) {
                int r = row0 + wm * 64 + i * 16 + (lane >> 4) * 4 + q;
                if (r >= M) continue;
                float val = acc[i][j][q] + bv;
                if (C) C[(size_t)r * ldc + c] = val;
                else if (c < 256)
                    xsb[((size_t)(c >> 5) * N_NODES + r) * 32 + (c & 31)] = __float2bfloat16(val);
                else if (c < 512) {
                    int c2 = c - 256;
                    linbb[((size_t)(c2 >> 5) * N_NODES + r) * 32 + (c2 & 31)] = __float2bfloat16(val);
                } else
                    aout[(size_t)r * 8 + (c - 512)] = val;
            }
        }
    }
}

// ---------------- XCD-sharded CSR gather-aggregation ----------------
// grid = 8 * ceil(N/4); group = blockIdx % 8 -> XCD round-robin puts one
// 3.2MB message slice per XCD L2 (vs 25.6MB full table). esrc/linb are
// streamed (no residency needed). Wave = 1 node: 4 edge-slots x 16 lanes,
// ushort2/lane (64B row-slice per edge). shfl-combine once per node.
#define LEAKY_EXP(vv) __expf(((vv) > 0.f) ? (vv) : 0.2f * (vv))

__global__ __launch_bounds__(256) void k_agg(
    const __hip_bfloat16* __restrict__ xsb2,   // [8][N][32]
    const __hip_bfloat16* __restrict__ linb2,  // [8][N][32]
    const float* __restrict__ a,               // [N][8]
    const int* __restrict__ rowptr, const int* __restrict__ esrc,
    const float* __restrict__ bg, const float* __restrict__ lb,
    __hip_bfloat16* __restrict__ hout) {       // [N][256]
    int g = blockIdx.x & 7;
    int nb = blockIdx.x >> 3;
    int wave = threadIdx.x >> 6;
    int lane = threadIdx.x & 63;
    int n = nb * 4 + wave;
    if (n >= N_NODES) return;
    int slot = lane >> 4, l16 = lane & 15;
    int cg = g * 32 + l16 * 2;
    int h = g >> 1;
    const __hip_bfloat16* xg = xsb2 + (size_t)g * N_NODES * 32;
    float ad = a[(size_t)n * 8 + 4 + h];
    int beg = rowptr[n], end = rowptr[n + 1];
    float a0 = 0.f, a1 = 0.f, dsum = 0.f;
    int k = beg;
    for (; k + 8 <= end; k += 8) {
        int s0 = esrc[k + slot];
        int s1 = esrc[k + 4 + slot];
        ushort2 m0 = *(const ushort2*)(xg + (size_t)s0 * 32 + l16 * 2);
        ushort2 m1 = *(const ushort2*)(xg + (size_t)s1 * 32 + l16 * 2);
        float av0 = a[(size_t)s0 * 8 + h];
        float av1 = a[(size_t)s1 * 8 + h];
        float e0 = LEAKY_EXP(av0 + ad);
        float e1 = LEAKY_EXP(av1 + ad);
        a0 += bfu(m0.x) * e0 + bfu(m1.x) * e1;
        a1 += bfu(m0.y) * e0 + bfu(m1.y) * e1;
        dsum += e0 + e1;
    }
    for (; k < end; k += 4) {
        int idx = k + slot;
        bool valid = idx < end;
        int s = esrc[valid ? idx : (end - 1)];
        ushort2 m = *(const ushort2*)(xg + (size_t)s * 32 + l16 * 2);
        float av = a[(size_t)s * 8 + h];
        float ev = valid ? LEAKY_EXP(av + ad) : 0.f;
        a0 += bfu(m.x) * ev;
        a1 += bfu(m.y) * ev;
        dsum += ev;
    }
    a0 += __shfl_xor(a0, 16, 64); a0 += __shfl_xor(a0, 32, 64);
    a1 += __shfl_xor(a1, 16, 64); a1 += __shfl_xor(a1, 32, 64);
    dsum += __shfl_xor(dsum, 16, 64); dsum += __shfl_xor(dsum, 32, 64);
    if (slot == 0) {
        float inv = 1.f / (dsum + 1e-16f);
        float2 bgv = *(const float2*)(bg + cg);
        float2 lbv = *(const float2*)(lb + cg);
        ushort2 lnv = *(const ushort2*)(linb2 + ((size_t)g * N_NODES + n) * 32 + l16 * 2);
        ushort2 o;
        o.x = b16(a0 * inv + bgv.x + bfu(lnv.x) + lbv.x);
        o.y = b16(a1 * inv + bgv.y + bfu(lnv.y) + lbv.y);
        *(ushort2*)(hout + (size_t)n * 256 + cg) = o;
    }
}

// ---------------- BatchNorm ----------------
__global__ void k_bnstats(const __hip_bfloat16* __restrict__ hb,
                          float* __restrict__ bnsum, float* __restrict__ bnsq) {
    int c = threadIdx.x;
    float s = 0.f, q = 0.f;
    for (int r = blockIdx.x; r < N_NODES; r += gridDim.x) {
        float v = __bfloat162float(hb[(size_t)r * 256 + c]);
        s += v; q += v * v;
    }
    atomicAdd(&bnsum[c], s);
    atomicAdd(&bnsq[c], q);
}

__global__ __launch_bounds__(256) void k_bnapply(
    const __hip_bfloat16* __restrict__ hb, __hip_bfloat16* __restrict__ hpost,
    const float* __restrict__ bnsum, const float* __restrict__ bnsq,
    const float* __restrict__ g, const float* __restrict__ b) {
    __shared__ float sA[256], sB[256];
    int t = threadIdx.x;
    {
        float m = bnsum[t] / (float)N_NODES;
        float v = bnsq[t] / (float)N_NODES - m * m;
        float rs = rsqrtf(v + 1e-5f) * g[t];
        sA[t] = rs;
        sB[t] = b[t] - m * rs;
    }
    __syncthreads();
    size_t tot = (size_t)N_NODES * 256;
    for (size_t i = (size_t)blockIdx.x * 256 + t; i < tot;
         i += (size_t)gridDim.x * 256) {
        int c = (int)(i & 255);
        float v = __bfloat162float(hb[i]) * sA[c] + sB[c];
        v = v > 0.f ? v : 0.f;
        hpost[i] = __float2bfloat16(v);
    }
}

// ---------------- host ----------------
extern "C" void kernel_launch(void* const* d_in, const int* in_sizes, int n_in,
                              void* d_out, int out_size, void* d_ws, size_t ws_size,
                              hipStream_t stream) {
    const float* x     = (const float*)d_in[0];
    const int*   ei    = (const int*)d_in[1];
    const float* ws0   = (const float*)d_in[2];
    const float* wd0   = (const float*)d_in[3];
    const float* atts0 = (const float*)d_in[4];
    const float* attd0 = (const float*)d_in[5];
    const float* bg0   = (const float*)d_in[6];
    const float* lw0   = (const float*)d_in[7];
    const float* lb0   = (const float*)d_in[8];
    const float* g0    = (const float*)d_in[9];
    const float* b0    = (const float*)d_in[10];
    const float* ws1   = (const float*)d_in[11];
    const float* wd1   = (const float*)d_in[12];
    const float* atts1 = (const float*)d_in[13];
    const float* attd1 = (const float*)d_in[14];
    const float* bg1   = (const float*)d_in[15];
    const float* lw1   = (const float*)d_in[16];
    const float* lb1   = (const float*)d_in[17];
    const float* g1    = (const float*)d_in[18];
    const float* b1    = (const float*)d_in[19];
    const float* fcw   = (const float*)d_in[20];
    const float* fcb   = (const float*)d_in[21];
    float* out = (float*)d_out;

    char* p = (char*)d_ws;
    auto alloc = [&](size_t bytes) -> char* {
        char* r = p;
        p += (bytes + 255) & ~(size_t)255;
        return r;
    };
    __hip_bfloat16* xsb   = (__hip_bfloat16*)alloc((size_t)N_NODES * 256 * 2);  // [8][N][32]
    __hip_bfloat16* linb  = (__hip_bfloat16*)alloc((size_t)N_NODES * 256 * 2);  // [8][N][32]
    __hip_bfloat16* hb    = (__hip_bfloat16*)alloc((size_t)N_NODES * 256 * 2);
    __hip_bfloat16* hpost = (__hip_bfloat16*)alloc((size_t)MPAD * 256 * 2);
    unsigned short* xb    = (unsigned short*)alloc((size_t)MPAD * 128 * 2);
    float* a      = (float*)alloc((size_t)N_NODES * 8 * 4);
    int*   esrc   = (int*)alloc((size_t)N_EDGES * 4);
    int*   rowptr = (int*)alloc((size_t)(N_NODES + 1) * 4);
    int*   bsum   = (int*)alloc(64 * 4);
    unsigned short* w0b = (unsigned short*)alloc((size_t)640 * 128 * 2);
    unsigned short* w1b = (unsigned short*)alloc((size_t)640 * 256 * 2);
    unsigned short* fcb16 = (unsigned short*)alloc((size_t)384 * 256 * 2);
    float* wtil   = (float*)alloc((size_t)256 * 8 * 4);
    int*   flag   = (int*)alloc(256);
    size_t zr_bytes = (size_t)N_NODES * 4 * 2 + 4 * 256 * 4;
    char* zbase = alloc(zr_bytes);
    int*   deg    = (int*)zbase;
    int*   cursor = deg + N_NODES;
    float* bnsum0 = (float*)(cursor + N_NODES);
    float* bnsq0  = bnsum0 + 256;
    float* bnsum1 = bnsq0 + 256;
    float* bnsq1  = bnsum1 + 256;

    hipMemsetAsync(zbase, 0, zr_bytes, stream);

    const int EB = (N_EDGES + 255) / 256;
    const int RB = MPAD / 128;                 // 391
    const int AB = 8 * ((N_NODES + 3) / 4);    // 8 channel-groups x node-blocks
    const int SB = (N_NODES + 1023) / 1024;    // 49

    k_detect<<<1, 1, 0, stream>>>((const unsigned*)ei, flag);
    k_deg<<<EB, 256, 0, stream>>>(ei, flag, deg);
    k_scan1<<<SB, 256, 0, stream>>>(deg, rowptr, bsum);
    k_scan2<<<1, 64, 0, stream>>>(bsum, SB, rowptr);
    k_scan3<<<SB, 256, 0, stream>>>(rowptr, bsum);
    k_fill<<<EB, 256, 0, stream>>>(ei, flag, rowptr, cursor, esrc);

    // weight prep
    k_wtilde<<<(128 * 8 + 255) / 256, 256, 0, stream>>>(ws0, wd0, atts0, attd0, wtil, 128);
    k_wcat_t<<<(640 * 128 + 255) / 256, 256, 0, stream>>>(ws0, lw0, wtil, 128, w0b);
    k_wtilde<<<(256 * 8 + 255) / 256, 256, 0, stream>>>(ws1, wd1, atts1, attd1, wtil, 256);
    k_wcat_t<<<(640 * 256 + 255) / 256, 256, 0, stream>>>(ws1, lw1, wtil, 256, w1b);
    k_fcw_t<<<(384 * 256 + 255) / 256, 256, 0, stream>>>(fcw, 256, fcb16);
    k_xcast<<<2048, 256, 0, stream>>>(x, xb);

    // ---- layer 0 (d = 128) ----
    k_gemm1<<<dim3(RB, 5), 256, 0, stream>>>(xb, w0b,
                                             nullptr, 0, xsb, linb, a,
                                             nullptr, N_NODES, 128, 520);
    k_agg<<<AB, 256, 0, stream>>>(xsb, linb, a, rowptr, esrc, bg0, lb0, hb);
    k_bnstats<<<1024, 256, 0, stream>>>(hb, bnsum0, bnsq0);
    k_bnapply<<<2048, 256, 0, stream>>>(hb, hpost, bnsum0, bnsq0, g0, b0);

    // ---- layer 1 (d = 256) ----
    k_gemm1<<<dim3(RB, 5), 256, 0, stream>>>((const unsigned short*)hpost, w1b,
                                             nullptr, 0, xsb, linb, a,
                                             nullptr, N_NODES, 256, 520);
    k_agg<<<AB, 256, 0, stream>>>(xsb, linb, a, rowptr, esrc, bg1, lb1, hb);
    k_bnstats<<<1024, 256, 0, stream>>>(hb, bnsum1, bnsq1);
    k_bnapply<<<2048, 256, 0, stream>>>(hb, hpost, bnsum1, bnsq1, g1, b1);

    // ---- final FC ----
    k_gemm1<<<dim3(RB, 3), 256, 0, stream>>>((const unsigned short*)hpost, fcb16,
                                             out, NCLS, nullptr, nullptr, nullptr,
                                             fcb, N_NODES, 256, NCLS);
}

// Round 16
// 555.422 us; speedup vs baseline: 1.3689x; 1.3689x over previous
//
#include <hip/hip_runtime.h>
#include <hip/hip_bf16.h>
#include <math.h>

#define N_NODES 50000
#define MPAD 50048      // padded row count for GEMM A-tiles (128-multiple)
#define N_EDGES 800000
#define HCH 256
#define NHEAD 4
#define HIDC 64
#define NCLS 349
#define F_IN 128

typedef short short8 __attribute__((ext_vector_type(8)));
typedef float floatx4 __attribute__((ext_vector_type(4)));

// ---------------- edge_index storage-width detection ----------------
__global__ void k_detect(const unsigned* ei, int* flag) {
    if (blockIdx.x == 0 && threadIdx.x == 0) {
        int i64 = 1;
        for (int e = 0; e < 64; e++)
            if (ei[2 * e + 1] != 0u) { i64 = 0; break; }
        *flag = i64;
    }
}

__device__ __forceinline__ void edge_sd(const int* ei, int e, int i64, int& s, int& d) {
    if (i64) {
        const long long* p = (const long long*)ei;
        s = (int)p[e]; d = (int)p[N_EDGES + e];
    } else {
        s = ei[e]; d = ei[N_EDGES + e];
    }
}

// ---------------- CSR build (by dst) ----------------
__global__ void k_deg(const int* ei, const int* flag, int* deg) {
    int e = blockIdx.x * 256 + threadIdx.x;
    if (e >= N_EDGES) return;
    int s, d; edge_sd(ei, e, *flag, s, d);
    atomicAdd(&deg[d], 1);
}

__global__ __launch_bounds__(256) void k_scan1(const int* __restrict__ deg,
                                               int* __restrict__ rowptr,
                                               int* __restrict__ bsum) {
    __shared__ int sd[256];
    int t = threadIdx.x;
    int base = blockIdx.x * 1024 + t * 4;
    int d0 = 0, d1 = 0, d2 = 0, d3 = 0;
    if (base + 3 < N_NODES) {
        int4 v = *(const int4*)(deg + base);
        d0 = v.x; d1 = v.y; d2 = v.z; d3 = v.w;
    } else {
        if (base + 0 < N_NODES) d0 = deg[base + 0];
        if (base + 1 < N_NODES) d1 = deg[base + 1];
        if (base + 2 < N_NODES) d2 = deg[base + 2];
        if (base + 3 < N_NODES) d3 = deg[base + 3];
    }
    int ts = d0 + d1 + d2 + d3;
    sd[t] = ts;
    __syncthreads();
    #pragma unroll
    for (int off = 1; off < 256; off <<= 1) {
        int v = (t >= off) ? sd[t - off] : 0;
        __syncthreads();
        sd[t] += v;
        __syncthreads();
    }
    int excl = (t == 0) ? 0 : sd[t - 1];
    if (base + 0 < N_NODES) rowptr[base + 0] = excl;
    if (base + 1 < N_NODES) rowptr[base + 1] = excl + d0;
    if (base + 2 < N_NODES) rowptr[base + 2] = excl + d0 + d1;
    if (base + 3 < N_NODES) rowptr[base + 3] = excl + d0 + d1 + d2;
    if (t == 255) bsum[blockIdx.x] = sd[255];
}

__global__ void k_scan2(int* __restrict__ bsum, int nb, int* __restrict__ rowptr) {
    int lane = threadIdx.x;
    int orig = (lane < nb) ? bsum[lane] : 0;
    int v = orig;
    #pragma unroll
    for (int off = 1; off < 64; off <<= 1) {
        int tv = __shfl_up(v, off, 64);
        if (lane >= off) v += tv;
    }
    if (lane < nb) bsum[lane] = v - orig;
    if (lane == 0) rowptr[N_NODES] = N_EDGES;
}

__global__ __launch_bounds__(256) void k_scan3(int* __restrict__ rowptr,
                                               const int* __restrict__ bsum) {
    int base = blockIdx.x * 1024 + threadIdx.x * 4;
    int off = bsum[blockIdx.x];
    if (base + 3 < N_NODES) {
        int4 v = *(int4*)(rowptr + base);
        v.x += off; v.y += off; v.z += off; v.w += off;
        *(int4*)(rowptr + base) = v;
    } else {
        for (int j = 0; j < 4; j++)
            if (base + j < N_NODES) rowptr[base + j] += off;
    }
}

__global__ void k_fill(const int* ei, const int* flag, const int* __restrict__ rowptr,
                       int* cursor, int* __restrict__ esrc) {
    int e = blockIdx.x * 256 + threadIdx.x;
    if (e >= N_EDGES) return;
    int s, d; edge_sd(ei, e, *flag, s, d);
    int pos = atomicAdd(&cursor[d], 1);
    esrc[rowptr[d] + pos] = s;
}

// ---------------- attention-score folding ----------------
__global__ void k_wtilde(const float* __restrict__ ws, const float* __restrict__ wd,
                         const float* __restrict__ atts, const float* __restrict__ attd,
                         float* __restrict__ wt, int d) {
    int id = blockIdx.x * 256 + threadIdx.x;
    if (id >= d * 8) return;
    int j = id & 7, k = id >> 3;
    const float* w = (j < 4) ? ws : wd;
    const float* at = (j < 4) ? atts : attd;
    int h = j & 3;
    float s = 0.f;
    for (int c = 0; c < HIDC; c++) s += w[k * HCH + h * HIDC + c] * at[h * HIDC + c];
    wt[k * 8 + j] = s;
}

// ---------------- bf16 helpers ----------------
__device__ __forceinline__ unsigned short b16(float v) {
    __hip_bfloat16 t = __float2bfloat16(v);
    return *(unsigned short*)&t;
}

__device__ __forceinline__ float bfu(unsigned short u) {
    unsigned v = (unsigned)u << 16;
    return __builtin_bit_cast(float, v);
}

__global__ __launch_bounds__(256) void k_xcast(const float* __restrict__ x,
                                               unsigned short* __restrict__ xb) {
    size_t tot = (size_t)N_NODES * 128 / 4;
    for (size_t i = (size_t)blockIdx.x * 256 + threadIdx.x; i < tot;
         i += (size_t)gridDim.x * 256) {
        float4 v = *(const float4*)(x + i * 4);
        ushort4 o = {b16(v.x), b16(v.y), b16(v.z), b16(v.w)};
        *(ushort4*)(xb + i * 4) = o;
    }
}

// fused weight, transposed, plain bf16: Bt[c][k], c in [0,640)
__global__ void k_wcat_t(const float* __restrict__ ws, const float* __restrict__ lw,
                         const float* __restrict__ wtil, int K,
                         unsigned short* __restrict__ Bb) {
    int id = blockIdx.x * 256 + threadIdx.x;
    if (id >= 640 * K) return;
    int c = id / K, k = id % K;
    float v;
    if (c < 256) v = ws[(size_t)k * 256 + c];
    else if (c < 512) v = lw[(size_t)k * 256 + (c - 256)];
    else if (c < 520) v = wtil[(size_t)k * 8 + (c - 512)];
    else v = 0.f;
    Bb[(size_t)c * K + k] = b16(v);
}

__global__ void k_fcw_t(const float* __restrict__ fcw, int K,
                        unsigned short* __restrict__ Bb) {
    int id = blockIdx.x * 256 + threadIdx.x;
    if (id >= 384 * K) return;
    int c = id / K, k = id % K;
    float v = (c < NCLS) ? fcw[(size_t)k * NCLS + c] : 0.f;
    Bb[(size_t)c * K + k] = b16(v);
}

// ---------------- global_load_lds helper ----------------
__device__ __forceinline__ void gload16(const void* g, void* l) {
    __builtin_amdgcn_global_load_lds(
        (const __attribute__((address_space(1))) void*)g,
        (__attribute__((address_space(3))) void*)l, 16, 0, 0);
}

// ---------------- 2-phase MFMA GEMM, counted vmcnt + dead-fragment skip ----
// Row-major epilogue (R14 layouts; R15's sharded layout reverted).
__global__ __launch_bounds__(256) void k_gemm1(
    const unsigned short* __restrict__ Ab,
    const unsigned short* __restrict__ Bb,
    float* __restrict__ C, int ldc, __hip_bfloat16* __restrict__ xsb,
    __hip_bfloat16* __restrict__ linbb, float* __restrict__ aout,
    const float* __restrict__ bias, int M, int K, int Nc) {
    __shared__ unsigned short sA[2][4096];
    __shared__ unsigned short sB[2][4096];
    int tid = threadIdx.x;
    int lane = tid & 63, wave = tid >> 6;
    int wm = wave >> 1, wn = wave & 1;
    int row0 = blockIdx.x * 128, col0 = blockIdx.y * 128;

    int rowq[2], kcq[2];
    #pragma unroll
    for (int q = 0; q < 2; q++) {
        int lds16 = wave * 128 + q * 64 + lane;
        int line = lds16 >> 3;
        int slot0 = (lds16 & 7) ^ (line & 7);
        rowq[q] = (line << 1) | (slot0 >> 2);
        kcq[q] = slot0 & 3;
    }
    int kc = lane >> 4, fr = lane & 15;
    int offA[4], offB[4];
    bool usej[4];
    #pragma unroll
    for (int i = 0; i < 4; i++) {
        int ar = wm * 64 + i * 16 + fr;
        int ln = ar >> 1;
        int sl = (((ar & 1) << 2) | kc) ^ (ln & 7);
        offA[i] = ln * 128 + sl * 16;
        int bc = wn * 64 + i * 16 + fr;
        ln = bc >> 1;
        sl = (((bc & 1) << 2) | kc) ^ (ln & 7);
        offB[i] = ln * 128 + sl * 16;
        usej[i] = (col0 + wn * 64 + i * 16) < Nc;   // dead-column fragment skip
    }

    const int nt = K >> 5;
    #pragma unroll
    for (int q = 0; q < 2; q++) {
        int lb = wave * 2048 + q * 1024;
        gload16(Ab + (size_t)(row0 + rowq[q]) * K + kcq[q] * 8, (char*)sA[0] + lb);
        gload16(Bb + (size_t)(col0 + rowq[q]) * K + kcq[q] * 8, (char*)sB[0] + lb);
    }

    floatx4 acc[4][4] = {};
    int cur = 0;
    for (int t = 0; t < nt; t++) {
        if (t + 1 < nt) {
            int k0 = (t + 1) << 5;
            #pragma unroll
            for (int q = 0; q < 2; q++) {
                int lb = wave * 2048 + q * 1024;
                gload16(Ab + (size_t)(row0 + rowq[q]) * K + k0 + kcq[q] * 8, (char*)sA[cur ^ 1] + lb);
                gload16(Bb + (size_t)(col0 + rowq[q]) * K + k0 + kcq[q] * 8, (char*)sB[cur ^ 1] + lb);
            }
            asm volatile("s_waitcnt vmcnt(4)" ::: "memory");
        } else {
            asm volatile("s_waitcnt vmcnt(0)" ::: "memory");
        }
        __builtin_amdgcn_s_barrier();
        __builtin_amdgcn_sched_barrier(0);
        short8 fah[4], fbh[4];
        #pragma unroll
        for (int i = 0; i < 4; i++) {
            fah[i] = *(const short8*)((const char*)sA[cur] + offA[i]);
            if (usej[i]) fbh[i] = *(const short8*)((const char*)sB[cur] + offB[i]);
        }
        #pragma unroll
        for (int i = 0; i < 4; i++)
            #pragma unroll
            for (int j = 0; j < 4; j++)
                if (usej[j])
                    acc[i][j] = __builtin_amdgcn_mfma_f32_16x16x32_bf16(fah[i], fbh[j], acc[i][j], 0, 0, 0);
        asm volatile("s_waitcnt lgkmcnt(0)" ::: "memory");
        __builtin_amdgcn_s_barrier();
        __builtin_amdgcn_sched_barrier(0);
        cur ^= 1;
    }
    #pragma unroll
    for (int i = 0; i < 4; i++) {
        #pragma unroll
        for (int j = 0; j < 4; j++) {
            if (!usej[j]) continue;
            int c = col0 + wn * 64 + j * 16 + fr;
            if (c >= Nc) continue;
            float bv = bias ? bias[c] : 0.f;
            #pragma unroll
            for (int q = 0; q < 4; q++) {
                int r = row0 + wm * 64 + i * 16 + (lane >> 4) * 4 + q;
                if (r >= M) continue;
                float val = acc[i][j][q] + bv;
                if (C) C[(size_t)r * ldc + c] = val;
                else if (c < 256) xsb[(size_t)r * 256 + c] = __float2bfloat16(val);
                else if (c < 512) linbb[(size_t)r * 256 + (c - 256)] = __float2bfloat16(val);
                else aout[(size_t)r * 8 + (c - 512)] = val;
            }
        }
    }
}

// ---------------- fused CSR gather-aggregation (R13/R14 half-wave split) ----
#define LEAKY_EXP(vv) __expf(((vv) > 0.f) ? (vv) : 0.2f * (vv))

__global__ __launch_bounds__(256) void k_agg(
    const __hip_bfloat16* __restrict__ xsb,
    const __hip_bfloat16* __restrict__ linb, const float* __restrict__ a,
    const int* __restrict__ rowptr, const int* __restrict__ esrc,
    const float* __restrict__ bg, const float* __restrict__ lb,
    __hip_bfloat16* __restrict__ hout) {
    int wave = threadIdx.x >> 6;
    int lane = threadIdx.x & 63;
    int n = blockIdx.x * 4 + wave;
    if (n >= N_NODES) return;
    int half = lane >> 5;
    int l32 = lane & 31;
    int c0 = l32 * 8;
    int h = l32 >> 3;
    float ad = a[(size_t)n * 8 + 4 + h];
    int beg = rowptr[n], end = rowptr[n + 1];
    float acc[8] = {};
    float dsum = 0.f;
    int k = beg;
    for (; k + 8 <= end; k += 8) {
        int sb = k + half * 4;
        int s[4];
        #pragma unroll
        for (int u = 0; u < 4; u++) s[u] = esrc[sb + u];
        short8 m[4];
        #pragma unroll
        for (int u = 0; u < 4; u++)
            m[u] = *(const short8*)(xsb + (size_t)s[u] * 256 + c0);
        float av[4];
        #pragma unroll
        for (int u = 0; u < 4; u++) av[u] = a[(size_t)s[u] * 8 + h];
        #pragma unroll
        for (int u = 0; u < 4; u++) {
            float ev = LEAKY_EXP(av[u] + ad);
            #pragma unroll
            for (int j = 0; j < 8; j++)
                acc[j] += bfu((unsigned short)m[u][j]) * ev;
            dsum += ev;
        }
    }
    for (; k < end; k += 2) {
        int idx = k + half;
        bool valid = idx < end;
        int s = esrc[valid ? idx : (end - 1)];
        short8 m = *(const short8*)(xsb + (size_t)s * 256 + c0);
        float av = a[(size_t)s * 8 + h];
        float ev = valid ? LEAKY_EXP(av + ad) : 0.f;
        #pragma unroll
        for (int j = 0; j < 8; j++)
            acc[j] += bfu((unsigned short)m[j]) * ev;
        dsum += ev;
    }
    #pragma unroll
    for (int j = 0; j < 8; j++) acc[j] += __shfl_xor(acc[j], 32, 64);
    dsum += __shfl_xor(dsum, 32, 64);
    if (lane < 32) {
        float inv = 1.f / (dsum + 1e-16f);
        float4 bg0 = *(const float4*)(bg + c0);
        float4 bg1 = *(const float4*)(bg + c0 + 4);
        float4 lb0 = *(const float4*)(lb + c0);
        float4 lb1 = *(const float4*)(lb + c0 + 4);
        float bgv[8] = {bg0.x, bg0.y, bg0.z, bg0.w, bg1.x, bg1.y, bg1.z, bg1.w};
        float lbv[8] = {lb0.x, lb0.y, lb0.z, lb0.w, lb1.x, lb1.y, lb1.z, lb1.w};
        short8 lnv = *(const short8*)(linb + (size_t)n * 256 + c0);
        short8 o;
        #pragma unroll
        for (int j = 0; j < 8; j++)
            o[j] = (short)b16(acc[j] * inv + bgv[j] + bfu((unsigned short)lnv[j]) + lbv[j]);
        *(short8*)(hout + (size_t)n * 256 + c0) = o;
    }
}

// ---------------- BatchNorm ----------------
__global__ void k_bnstats(const __hip_bfloat16* __restrict__ hb,
                          float* __restrict__ bnsum, float* __restrict__ bnsq) {
    int c = threadIdx.x;
    float s = 0.f, q = 0.f;
    for (int r = blockIdx.x; r < N_NODES; r += gridDim.x) {
        float v = __bfloat162float(hb[(size_t)r * 256 + c]);
        s += v; q += v * v;
    }
    atomicAdd(&bnsum[c], s);
    atomicAdd(&bnsq[c], q);
}

__global__ __launch_bounds__(256) void k_bnapply(
    const __hip_bfloat16* __restrict__ hb, __hip_bfloat16* __restrict__ hpost,
    const float* __restrict__ bnsum, const float* __restrict__ bnsq,
    const float* __restrict__ g, const float* __restrict__ b) {
    __shared__ float sA[256], sB[256];
    int t = threadIdx.x;
    {
        float m = bnsum[t] / (float)N_NODES;
        float v = bnsq[t] / (float)N_NODES - m * m;
        float rs = rsqrtf(v + 1e-5f) * g[t];
        sA[t] = rs;
        sB[t] = b[t] - m * rs;
    }
    __syncthreads();
    size_t tot = (size_t)N_NODES * 256;
    for (size_t i = (size_t)blockIdx.x * 256 + t; i < tot;
         i += (size_t)gridDim.x * 256) {
        int c = (int)(i & 255);
        float v = __bfloat162float(hb[i]) * sA[c] + sB[c];
        v = v > 0.f ? v : 0.f;
        hpost[i] = __float2bfloat16(v);
    }
}

// ---------------- host ----------------
extern "C" void kernel_launch(void* const* d_in, const int* in_sizes, int n_in,
                              void* d_out, int out_size, void* d_ws, size_t ws_size,
                              hipStream_t stream) {
    const float* x     = (const float*)d_in[0];
    const int*   ei    = (const int*)d_in[1];
    const float* ws0   = (const float*)d_in[2];
    const float* wd0   = (const float*)d_in[3];
    const float* atts0 = (const float*)d_in[4];
    const float* attd0 = (const float*)d_in[5];
    const float* bg0   = (const float*)d_in[6];
    const float* lw0   = (const float*)d_in[7];
    const float* lb0   = (const float*)d_in[8];
    const float* g0    = (const float*)d_in[9];
    const float* b0    = (const float*)d_in[10];
    const float* ws1   = (const float*)d_in[11];
    const float* wd1   = (const float*)d_in[12];
    const float* atts1 = (const float*)d_in[13];
    const float* attd1 = (const float*)d_in[14];
    const float* bg1   = (const float*)d_in[15];
    const float* lw1   = (const float*)d_in[16];
    const float* lb1   = (const float*)d_in[17];
    const float* g1    = (const float*)d_in[18];
    const float* b1    = (const float*)d_in[19];
    const float* fcw   = (const float*)d_in[20];
    const float* fcb   = (const float*)d_in[21];
    float* out = (float*)d_out;

    char* p = (char*)d_ws;
    auto alloc = [&](size_t bytes) -> char* {
        char* r = p;
        p += (bytes + 255) & ~(size_t)255;
        return r;
    };
    __hip_bfloat16* xsb   = (__hip_bfloat16*)alloc((size_t)N_NODES * 256 * 2);
    __hip_bfloat16* linb  = (__hip_bfloat16*)alloc((size_t)N_NODES * 256 * 2);
    __hip_bfloat16* hb    = (__hip_bfloat16*)alloc((size_t)N_NODES * 256 * 2);
    __hip_bfloat16* hpost = (__hip_bfloat16*)alloc((size_t)MPAD * 256 * 2);
    unsigned short* xb    = (unsigned short*)alloc((size_t)MPAD * 128 * 2);
    float* a      = (float*)alloc((size_t)N_NODES * 8 * 4);
    int*   esrc   = (int*)alloc((size_t)N_EDGES * 4);
    int*   rowptr = (int*)alloc((size_t)(N_NODES + 1) * 4);
    int*   bsum   = (int*)alloc(64 * 4);
    unsigned short* w0b = (unsigned short*)alloc((size_t)640 * 128 * 2);
    unsigned short* w1b = (unsigned short*)alloc((size_t)640 * 256 * 2);
    unsigned short* fcb16 = (unsigned short*)alloc((size_t)384 * 256 * 2);
    float* wtil   = (float*)alloc((size_t)256 * 8 * 4);
    int*   flag   = (int*)alloc(256);
    size_t zr_bytes = (size_t)N_NODES * 4 * 2 + 4 * 256 * 4;
    char* zbase = alloc(zr_bytes);
    int*   deg    = (int*)zbase;
    int*   cursor = deg + N_NODES;
    float* bnsum0 = (float*)(cursor + N_NODES);
    float* bnsq0  = bnsum0 + 256;
    float* bnsum1 = bnsq0 + 256;
    float* bnsq1  = bnsum1 + 256;

    hipMemsetAsync(zbase, 0, zr_bytes, stream);

    const int EB = (N_EDGES + 255) / 256;
    const int RB = MPAD / 128;                 // 391
    const int AB = (N_NODES + 3) / 4;
    const int SB = (N_NODES + 1023) / 1024;    // 49

    k_detect<<<1, 1, 0, stream>>>((const unsigned*)ei, flag);
    k_deg<<<EB, 256, 0, stream>>>(ei, flag, deg);
    k_scan1<<<SB, 256, 0, stream>>>(deg, rowptr, bsum);
    k_scan2<<<1, 64, 0, stream>>>(bsum, SB, rowptr);
    k_scan3<<<SB, 256, 0, stream>>>(rowptr, bsum);
    k_fill<<<EB, 256, 0, stream>>>(ei, flag, rowptr, cursor, esrc);

    // weight prep
    k_wtilde<<<(128 * 8 + 255) / 256, 256, 0, stream>>>(ws0, wd0, atts0, attd0, wtil, 128);
    k_wcat_t<<<(640 * 128 + 255) / 256, 256, 0, stream>>>(ws0, lw0, wtil, 128, w0b);
    k_wtilde<<<(256 * 8 + 255) / 256, 256, 0, stream>>>(ws1, wd1, atts1, attd1, wtil, 256);
    k_wcat_t<<<(640 * 256 + 255) / 256, 256, 0, stream>>>(ws1, lw1, wtil, 256, w1b);
    k_fcw_t<<<(384 * 256 + 255) / 256, 256, 0, stream>>>(fcw, 256, fcb16);
    k_xcast<<<2048, 256, 0, stream>>>(x, xb);

    // ---- layer 0 (d = 128) ----
    k_gemm1<<<dim3(RB, 5), 256, 0, stream>>>(xb, w0b,
                                             nullptr, 0, xsb, linb, a,
                                             nullptr, N_NODES, 128, 520);
    k_agg<<<AB, 256, 0, stream>>>(xsb, linb, a, rowptr, esrc, bg0, lb0, hb);
    k_bnstats<<<1024, 256, 0, stream>>>(hb, bnsum0, bnsq0);
    k_bnapply<<<2048, 256, 0, stream>>>(hb, hpost, bnsum0, bnsq0, g0, b0);

    // ---- layer 1 (d = 256) ----
    k_gemm1<<<dim3(RB, 5), 256, 0, stream>>>((const unsigned short*)hpost, w1b,
                                             nullptr, 0, xsb, linb, a,
                                             nullptr, N_NODES, 256, 520);
    k_agg<<<AB, 256, 0, stream>>>(xsb, linb, a, rowptr, esrc, bg1, lb1, hb);
    k_bnstats<<<1024, 256, 0, stream>>>(hb, bnsum1, bnsq1);
    k_bnapply<<<2048, 256, 0, stream>>>(hb, hpost, bnsum1, bnsq1, g1, b1);

    // ---- final FC ----
    k_gemm1<<<dim3(RB, 3), 256, 0, stream>>>((const unsigned short*)hpost, fcb16,
                                             out, NCLS, nullptr, nullptr, nullptr,
                                             fcb, N_NODES, 256, NCLS);
}

// Round 17
// 488.973 us; speedup vs baseline: 1.5549x; 1.1359x over previous
//
#include <hip/hip_runtime.h>
#include <hip/hip_bf16.h>
#include <math.h>

#define N_NODES 50000
#define MPAD 50048      // padded row count for GEMM A-tiles (128-multiple)
#define N_EDGES 800000
#define HCH 256
#define NHEAD 4
#define HIDC 64
#define NCLS 349
#define F_IN 128

typedef short short8 __attribute__((ext_vector_type(8)));
typedef float floatx4 __attribute__((ext_vector_type(4)));

// ---------------- edge_index storage-width detection ----------------
__global__ void k_detect(const unsigned* ei, int* flag) {
    if (blockIdx.x == 0 && threadIdx.x == 0) {
        int i64 = 1;
        for (int e = 0; e < 64; e++)
            if (ei[2 * e + 1] != 0u) { i64 = 0; break; }
        *flag = i64;
    }
}

__device__ __forceinline__ void edge_sd(const int* ei, int e, int i64, int& s, int& d) {
    if (i64) {
        const long long* p = (const long long*)ei;
        s = (int)p[e]; d = (int)p[N_EDGES + e];
    } else {
        s = ei[e]; d = ei[N_EDGES + e];
    }
}

// ---------------- CSR build (by dst) ----------------
__global__ void k_deg(const int* ei, const int* flag, int* deg) {
    int e = blockIdx.x * 256 + threadIdx.x;
    if (e >= N_EDGES) return;
    int s, d; edge_sd(ei, e, *flag, s, d);
    atomicAdd(&deg[d], 1);
}

__global__ __launch_bounds__(256) void k_scan1(const int* __restrict__ deg,
                                               int* __restrict__ rowptr,
                                               int* __restrict__ bsum) {
    __shared__ int sd[256];
    int t = threadIdx.x;
    int base = blockIdx.x * 1024 + t * 4;
    int d0 = 0, d1 = 0, d2 = 0, d3 = 0;
    if (base + 3 < N_NODES) {
        int4 v = *(const int4*)(deg + base);
        d0 = v.x; d1 = v.y; d2 = v.z; d3 = v.w;
    } else {
        if (base + 0 < N_NODES) d0 = deg[base + 0];
        if (base + 1 < N_NODES) d1 = deg[base + 1];
        if (base + 2 < N_NODES) d2 = deg[base + 2];
        if (base + 3 < N_NODES) d3 = deg[base + 3];
    }
    int ts = d0 + d1 + d2 + d3;
    sd[t] = ts;
    __syncthreads();
    #pragma unroll
    for (int off = 1; off < 256; off <<= 1) {
        int v = (t >= off) ? sd[t - off] : 0;
        __syncthreads();
        sd[t] += v;
        __syncthreads();
    }
    int excl = (t == 0) ? 0 : sd[t - 1];
    if (base + 0 < N_NODES) rowptr[base + 0] = excl;
    if (base + 1 < N_NODES) rowptr[base + 1] = excl + d0;
    if (base + 2 < N_NODES) rowptr[base + 2] = excl + d0 + d1;
    if (base + 3 < N_NODES) rowptr[base + 3] = excl + d0 + d1 + d2;
    if (t == 255) bsum[blockIdx.x] = sd[255];
}

__global__ void k_scan2(int* __restrict__ bsum, int nb, int* __restrict__ rowptr) {
    int lane = threadIdx.x;
    int orig = (lane < nb) ? bsum[lane] : 0;
    int v = orig;
    #pragma unroll
    for (int off = 1; off < 64; off <<= 1) {
        int tv = __shfl_up(v, off, 64);
        if (lane >= off) v += tv;
    }
    if (lane < nb) bsum[lane] = v - orig;
    if (lane == 0) rowptr[N_NODES] = N_EDGES;
}

__global__ __launch_bounds__(256) void k_scan3(int* __restrict__ rowptr,
                                               const int* __restrict__ bsum) {
    int base = blockIdx.x * 1024 + threadIdx.x * 4;
    int off = bsum[blockIdx.x];
    if (base + 3 < N_NODES) {
        int4 v = *(int4*)(rowptr + base);
        v.x += off; v.y += off; v.z += off; v.w += off;
        *(int4*)(rowptr + base) = v;
    } else {
        for (int j = 0; j < 4; j++)
            if (base + j < N_NODES) rowptr[base + j] += off;
    }
}

__global__ void k_fill(const int* ei, const int* flag, const int* __restrict__ rowptr,
                       int* cursor, int* __restrict__ esrc) {
    int e = blockIdx.x * 256 + threadIdx.x;
    if (e >= N_EDGES) return;
    int s, d; edge_sd(ei, e, *flag, s, d);
    int pos = atomicAdd(&cursor[d], 1);
    esrc[rowptr[d] + pos] = s;
}

// ---------------- attention-score folding ----------------
__global__ void k_wtilde(const float* __restrict__ ws, const float* __restrict__ wd,
                         const float* __restrict__ atts, const float* __restrict__ attd,
                         float* __restrict__ wt, int d) {
    int id = blockIdx.x * 256 + threadIdx.x;
    if (id >= d * 8) return;
    int j = id & 7, k = id >> 3;
    const float* w = (j < 4) ? ws : wd;
    const float* at = (j < 4) ? atts : attd;
    int h = j & 3;
    float s = 0.f;
    for (int c = 0; c < HIDC; c++) s += w[k * HCH + h * HIDC + c] * at[h * HIDC + c];
    wt[k * 8 + j] = s;
}

// ---------------- bf16 helpers ----------------
__device__ __forceinline__ unsigned short b16(float v) {
    __hip_bfloat16 t = __float2bfloat16(v);
    return *(unsigned short*)&t;
}

__device__ __forceinline__ float bfu(unsigned short u) {
    unsigned v = (unsigned)u << 16;
    return __builtin_bit_cast(float, v);
}

__global__ __launch_bounds__(256) void k_xcast(const float* __restrict__ x,
                                               unsigned short* __restrict__ xb) {
    size_t tot = (size_t)N_NODES * 128 / 4;
    for (size_t i = (size_t)blockIdx.x * 256 + threadIdx.x; i < tot;
         i += (size_t)gridDim.x * 256) {
        float4 v = *(const float4*)(x + i * 4);
        ushort4 o = {b16(v.x), b16(v.y), b16(v.z), b16(v.w)};
        *(ushort4*)(xb + i * 4) = o;
    }
}

// fused weight, transposed, plain bf16: Bt[c][k], c in [0,640)
__global__ void k_wcat_t(const float* __restrict__ ws, const float* __restrict__ lw,
                         const float* __restrict__ wtil, int K,
                         unsigned short* __restrict__ Bb) {
    int id = blockIdx.x * 256 + threadIdx.x;
    if (id >= 640 * K) return;
    int c = id / K, k = id % K;
    float v;
    if (c < 256) v = ws[(size_t)k * 256 + c];
    else if (c < 512) v = lw[(size_t)k * 256 + (c - 256)];
    else if (c < 520) v = wtil[(size_t)k * 8 + (c - 512)];
    else v = 0.f;
    Bb[(size_t)c * K + k] = b16(v);
}

__global__ void k_fcw_t(const float* __restrict__ fcw, int K,
                        unsigned short* __restrict__ Bb) {
    int id = blockIdx.x * 256 + threadIdx.x;
    if (id >= 384 * K) return;
    int c = id / K, k = id % K;
    float v = (c < NCLS) ? fcw[(size_t)k * NCLS + c] : 0.f;
    Bb[(size_t)c * K + k] = b16(v);
}

// ---------------- global_load_lds helper ----------------
__device__ __forceinline__ void gload16(const void* g, void* l) {
    __builtin_amdgcn_global_load_lds(
        (const __attribute__((address_space(1))) void*)g,
        (__attribute__((address_space(3))) void*)l, 16, 0, 0);
}

// ---------------- 2-phase MFMA GEMM with COUNTED vmcnt (exact R14) ----------
// stage(t+1); vmcnt(4) [t's loads retired, t+1 in flight]; barrier; compute;
// lgkmcnt(0); barrier. No conditionals in the MFMA body (R16 lesson: guards
// in a hand-pinned schedule cost far more than the skipped work).
__global__ __launch_bounds__(256) void k_gemm1(
    const unsigned short* __restrict__ Ab,
    const unsigned short* __restrict__ Bb,
    float* __restrict__ C, int ldc, __hip_bfloat16* __restrict__ xsb,
    __hip_bfloat16* __restrict__ linbb, float* __restrict__ aout,
    const float* __restrict__ bias, int M, int K, int Nc) {
    __shared__ unsigned short sA[2][4096];
    __shared__ unsigned short sB[2][4096];
    int tid = threadIdx.x;
    int lane = tid & 63, wave = tid >> 6;
    int wm = wave >> 1, wn = wave & 1;
    int row0 = blockIdx.x * 128, col0 = blockIdx.y * 128;

    int rowq[2], kcq[2];
    #pragma unroll
    for (int q = 0; q < 2; q++) {
        int lds16 = wave * 128 + q * 64 + lane;
        int line = lds16 >> 3;
        int slot0 = (lds16 & 7) ^ (line & 7);
        rowq[q] = (line << 1) | (slot0 >> 2);
        kcq[q] = slot0 & 3;
    }
    int kc = lane >> 4, fr = lane & 15;
    int offA[4], offB[4];
    #pragma unroll
    for (int i = 0; i < 4; i++) {
        int ar = wm * 64 + i * 16 + fr;
        int ln = ar >> 1;
        int sl = (((ar & 1) << 2) | kc) ^ (ln & 7);
        offA[i] = ln * 128 + sl * 16;
        int bc = wn * 64 + i * 16 + fr;
        ln = bc >> 1;
        sl = (((bc & 1) << 2) | kc) ^ (ln & 7);
        offB[i] = ln * 128 + sl * 16;
    }

    const int nt = K >> 5;
    #pragma unroll
    for (int q = 0; q < 2; q++) {
        int lb = wave * 2048 + q * 1024;
        gload16(Ab + (size_t)(row0 + rowq[q]) * K + kcq[q] * 8, (char*)sA[0] + lb);
        gload16(Bb + (size_t)(col0 + rowq[q]) * K + kcq[q] * 8, (char*)sB[0] + lb);
    }

    floatx4 acc[4][4] = {};
    int cur = 0;
    for (int t = 0; t < nt; t++) {
        if (t + 1 < nt) {
            int k0 = (t + 1) << 5;
            #pragma unroll
            for (int q = 0; q < 2; q++) {
                int lb = wave * 2048 + q * 1024;
                gload16(Ab + (size_t)(row0 + rowq[q]) * K + k0 + kcq[q] * 8, (char*)sA[cur ^ 1] + lb);
                gload16(Bb + (size_t)(col0 + rowq[q]) * K + k0 + kcq[q] * 8, (char*)sB[cur ^ 1] + lb);
            }
            asm volatile("s_waitcnt vmcnt(4)" ::: "memory");
        } else {
            asm volatile("s_waitcnt vmcnt(0)" ::: "memory");
        }
        __builtin_amdgcn_s_barrier();
        __builtin_amdgcn_sched_barrier(0);
        short8 fah[4], fbh[4];
        #pragma unroll
        for (int i = 0; i < 4; i++) {
            fah[i] = *(const short8*)((const char*)sA[cur] + offA[i]);
            fbh[i] = *(const short8*)((const char*)sB[cur] + offB[i]);
        }
        #pragma unroll
        for (int i = 0; i < 4; i++)
            #pragma unroll
            for (int j = 0; j < 4; j++)
                acc[i][j] = __builtin_amdgcn_mfma_f32_16x16x32_bf16(fah[i], fbh[j], acc[i][j], 0, 0, 0);
        asm volatile("s_waitcnt lgkmcnt(0)" ::: "memory");
        __builtin_amdgcn_s_barrier();
        __builtin_amdgcn_sched_barrier(0);
        cur ^= 1;
    }
    #pragma unroll
    for (int i = 0; i < 4; i++) {
        #pragma unroll
        for (int j = 0; j < 4; j++) {
            int c = col0 + wn * 64 + j * 16 + fr;
            if (c >= Nc) continue;
            float bv = bias ? bias[c] : 0.f;
            #pragma unroll
            for (int q = 0; q < 4; q++) {
                int r = row0 + wm * 64 + i * 16 + (lane >> 4) * 4 + q;
                if (r >= M) continue;
                float val = acc[i][j][q] + bv;
                if (C) C[(size_t)r * ldc + c] = val;
                else if (c < 256) xsb[(size_t)r * 256 + c] = __float2bfloat16(val);
                else if (c < 512) linbb[(size_t)r * 256 + (c - 256)] = __float2bfloat16(val);
                else aout[(size_t)r * 8 + (c - 512)] = val;
            }
        }
    }
}

// ---------------- fused CSR gather-aggregation (R13/R14 half-wave split) ----
#define LEAKY_EXP(vv) __expf(((vv) > 0.f) ? (vv) : 0.2f * (vv))

__global__ __launch_bounds__(256) void k_agg(
    const __hip_bfloat16* __restrict__ xsb,
    const __hip_bfloat16* __restrict__ linb, const float* __restrict__ a,
    const int* __restrict__ rowptr, const int* __restrict__ esrc,
    const float* __restrict__ bg, const float* __restrict__ lb,
    __hip_bfloat16* __restrict__ hout) {
    int wave = threadIdx.x >> 6;
    int lane = threadIdx.x & 63;
    int n = blockIdx.x * 4 + wave;
    if (n >= N_NODES) return;
    int half = lane >> 5;
    int l32 = lane & 31;
    int c0 = l32 * 8;
    int h = l32 >> 3;
    float ad = a[(size_t)n * 8 + 4 + h];
    int beg = rowptr[n], end = rowptr[n + 1];
    float acc[8] = {};
    float dsum = 0.f;
    int k = beg;
    for (; k + 8 <= end; k += 8) {
        int sb = k + half * 4;
        int s[4];
        #pragma unroll
        for (int u = 0; u < 4; u++) s[u] = esrc[sb + u];
        short8 m[4];
        #pragma unroll
        for (int u = 0; u < 4; u++)
            m[u] = *(const short8*)(xsb + (size_t)s[u] * 256 + c0);
        float av[4];
        #pragma unroll
        for (int u = 0; u < 4; u++) av[u] = a[(size_t)s[u] * 8 + h];
        #pragma unroll
        for (int u = 0; u < 4; u++) {
            float ev = LEAKY_EXP(av[u] + ad);
            #pragma unroll
            for (int j = 0; j < 8; j++)
                acc[j] += bfu((unsigned short)m[u][j]) * ev;
            dsum += ev;
        }
    }
    for (; k < end; k += 2) {
        int idx = k + half;
        bool valid = idx < end;
        int s = esrc[valid ? idx : (end - 1)];
        short8 m = *(const short8*)(xsb + (size_t)s * 256 + c0);
        float av = a[(size_t)s * 8 + h];
        float ev = valid ? LEAKY_EXP(av + ad) : 0.f;
        #pragma unroll
        for (int j = 0; j < 8; j++)
            acc[j] += bfu((unsigned short)m[j]) * ev;
        dsum += ev;
    }
    #pragma unroll
    for (int j = 0; j < 8; j++) acc[j] += __shfl_xor(acc[j], 32, 64);
    dsum += __shfl_xor(dsum, 32, 64);
    if (lane < 32) {
        float inv = 1.f / (dsum + 1e-16f);
        float4 bg0 = *(const float4*)(bg + c0);
        float4 bg1 = *(const float4*)(bg + c0 + 4);
        float4 lb0 = *(const float4*)(lb + c0);
        float4 lb1 = *(const float4*)(lb + c0 + 4);
        float bgv[8] = {bg0.x, bg0.y, bg0.z, bg0.w, bg1.x, bg1.y, bg1.z, bg1.w};
        float lbv[8] = {lb0.x, lb0.y, lb0.z, lb0.w, lb1.x, lb1.y, lb1.z, lb1.w};
        short8 lnv = *(const short8*)(linb + (size_t)n * 256 + c0);
        short8 o;
        #pragma unroll
        for (int j = 0; j < 8; j++)
            o[j] = (short)b16(acc[j] * inv + bgv[j] + bfu((unsigned short)lnv[j]) + lbv[j]);
        *(short8*)(hout + (size_t)n * 256 + c0) = o;
    }
}

// ---------------- BatchNorm ----------------
__global__ void k_bnstats(const __hip_bfloat16* __restrict__ hb,
                          float* __restrict__ bnsum, float* __restrict__ bnsq) {
    int c = threadIdx.x;
    float s = 0.f, q = 0.f;
    for (int r = blockIdx.x; r < N_NODES; r += gridDim.x) {
        float v = __bfloat162float(hb[(size_t)r * 256 + c]);
        s += v; q += v * v;
    }
    atomicAdd(&bnsum[c], s);
    atomicAdd(&bnsq[c], q);
}

__global__ __launch_bounds__(256) void k_bnapply(
    const __hip_bfloat16* __restrict__ hb, __hip_bfloat16* __restrict__ hpost,
    const float* __restrict__ bnsum, const float* __restrict__ bnsq,
    const float* __restrict__ g, const float* __restrict__ b) {
    __shared__ float sA[256], sB[256];
    int t = threadIdx.x;
    {
        float m = bnsum[t] / (float)N_NODES;
        float v = bnsq[t] / (float)N_NODES - m * m;
        float rs = rsqrtf(v + 1e-5f) * g[t];
        sA[t] = rs;
        sB[t] = b[t] - m * rs;
    }
    __syncthreads();
    size_t tot = (size_t)N_NODES * 256;
    for (size_t i = (size_t)blockIdx.x * 256 + t; i < tot;
         i += (size_t)gridDim.x * 256) {
        int c = (int)(i & 255);
        float v = __bfloat162float(hb[i]) * sA[c] + sB[c];
        v = v > 0.f ? v : 0.f;
        hpost[i] = __float2bfloat16(v);
    }
}

// ---------------- host ----------------
extern "C" void kernel_launch(void* const* d_in, const int* in_sizes, int n_in,
                              void* d_out, int out_size, void* d_ws, size_t ws_size,
                              hipStream_t stream) {
    const float* x     = (const float*)d_in[0];
    const int*   ei    = (const int*)d_in[1];
    const float* ws0   = (const float*)d_in[2];
    const float* wd0   = (const float*)d_in[3];
    const float* atts0 = (const float*)d_in[4];
    const float* attd0 = (const float*)d_in[5];
    const float* bg0   = (const float*)d_in[6];
    const float* lw0   = (const float*)d_in[7];
    const float* lb0   = (const float*)d_in[8];
    const float* g0    = (const float*)d_in[9];
    const float* b0    = (const float*)d_in[10];
    const float* ws1   = (const float*)d_in[11];
    const float* wd1   = (const float*)d_in[12];
    const float* atts1 = (const float*)d_in[13];
    const float* attd1 = (const float*)d_in[14];
    const float* bg1   = (const float*)d_in[15];
    const float* lw1   = (const float*)d_in[16];
    const float* lb1   = (const float*)d_in[17];
    const float* g1    = (const float*)d_in[18];
    const float* b1    = (const float*)d_in[19];
    const float* fcw   = (const float*)d_in[20];
    const float* fcb   = (const float*)d_in[21];
    float* out = (float*)d_out;

    char* p = (char*)d_ws;
    auto alloc = [&](size_t bytes) -> char* {
        char* r = p;
        p += (bytes + 255) & ~(size_t)255;
        return r;
    };
    __hip_bfloat16* xsb   = (__hip_bfloat16*)alloc((size_t)N_NODES * 256 * 2);
    __hip_bfloat16* linb  = (__hip_bfloat16*)alloc((size_t)N_NODES * 256 * 2);
    __hip_bfloat16* hb    = (__hip_bfloat16*)alloc((size_t)N_NODES * 256 * 2);
    __hip_bfloat16* hpost = (__hip_bfloat16*)alloc((size_t)MPAD * 256 * 2);
    unsigned short* xb    = (unsigned short*)alloc((size_t)MPAD * 128 * 2);
    float* a      = (float*)alloc((size_t)N_NODES * 8 * 4);
    int*   esrc   = (int*)alloc((size_t)N_EDGES * 4);
    int*   rowptr = (int*)alloc((size_t)(N_NODES + 1) * 4);
    int*   bsum   = (int*)alloc(64 * 4);
    unsigned short* w0b = (unsigned short*)alloc((size_t)640 * 128 * 2);
    unsigned short* w1b = (unsigned short*)alloc((size_t)640 * 256 * 2);
    unsigned short* fcb16 = (unsigned short*)alloc((size_t)384 * 256 * 2);
    float* wtil   = (float*)alloc((size_t)256 * 8 * 4);
    int*   flag   = (int*)alloc(256);
    size_t zr_bytes = (size_t)N_NODES * 4 * 2 + 4 * 256 * 4;
    char* zbase = alloc(zr_bytes);
    int*   deg    = (int*)zbase;
    int*   cursor = deg + N_NODES;
    float* bnsum0 = (float*)(cursor + N_NODES);
    float* bnsq0  = bnsum0 + 256;
    float* bnsum1 = bnsq0 + 256;
    float* bnsq1  = bnsum1 + 256;

    hipMemsetAsync(zbase, 0, zr_bytes, stream);

    const int EB = (N_EDGES + 255) / 256;
    const int RB = MPAD / 128;                 // 391
    const int AB = (N_NODES + 3) / 4;
    const int SB = (N_NODES + 1023) / 1024;    // 49

    k_detect<<<1, 1, 0, stream>>>((const unsigned*)ei, flag);
    k_deg<<<EB, 256, 0, stream>>>(ei, flag, deg);
    k_scan1<<<SB, 256, 0, stream>>>(deg, rowptr, bsum);
    k_scan2<<<1, 64, 0, stream>>>(bsum, SB, rowptr);
    k_scan3<<<SB, 256, 0, stream>>>(rowptr, bsum);
    k_fill<<<EB, 256, 0, stream>>>(ei, flag, rowptr, cursor, esrc);

    // weight prep
    k_wtilde<<<(128 * 8 + 255) / 256, 256, 0, stream>>>(ws0, wd0, atts0, attd0, wtil, 128);
    k_wcat_t<<<(640 * 128 + 255) / 256, 256, 0, stream>>>(ws0, lw0, wtil, 128, w0b);
    k_wtilde<<<(256 * 8 + 255) / 256, 256, 0, stream>>>(ws1, wd1, atts1, attd1, wtil, 256);
    k_wcat_t<<<(640 * 256 + 255) / 256, 256, 0, stream>>>(ws1, lw1, wtil, 256, w1b);
    k_fcw_t<<<(384 * 256 + 255) / 256, 256, 0, stream>>>(fcw, 256, fcb16);
    k_xcast<<<2048, 256, 0, stream>>>(x, xb);

    // ---- layer 0 (d = 128) ----
    k_gemm1<<<dim3(RB, 5), 256, 0, stream>>>(xb, w0b,
                                             nullptr, 0, xsb, linb, a,
                                             nullptr, N_NODES, 128, 520);
    k_agg<<<AB, 256, 0, stream>>>(xsb, linb, a, rowptr, esrc, bg0, lb0, hb);
    k_bnstats<<<1024, 256, 0, stream>>>(hb, bnsum0, bnsq0);
    k_bnapply<<<2048, 256, 0, stream>>>(hb, hpost, bnsum0, bnsq0, g0, b0);

    // ---- layer 1 (d = 256) ----
    k_gemm1<<<dim3(RB, 5), 256, 0, stream>>>((const unsigned short*)hpost, w1b,
                                             nullptr, 0, xsb, linb, a,
                                             nullptr, N_NODES, 256, 520);
    k_agg<<<AB, 256, 0, stream>>>(xsb, linb, a, rowptr, esrc, bg1, lb1, hb);
    k_bnstats<<<1024, 256, 0, stream>>>(hb, bnsum1, bnsq1);
    k_bnapply<<<2048, 256, 0, stream>>>(hb, hpost, bnsum1, bnsq1, g1, b1);

    // ---- final FC ----
    k_gemm1<<<dim3(RB, 3), 256, 0, stream>>>((const unsigned short*)hpost, fcb16,
                                             out, NCLS, nullptr, nullptr, nullptr,
                                             fcb, N_NODES, 256, NCLS);
}